// Round 2
// baseline (4312.114 us; speedup 1.0000x reference)
//
#include <hip/hip_runtime.h>
#include <cmath>
#include <cstdint>
#include <cstddef>

#define BB 256      // batch
#define MM 8192     // checks
#define NN 16384    // variables
#define DEG 10
#define MAX_ITER 30

// ---------------- prologue kernels ----------------

__global__ void k_init(int* colcnt, int* colfill, unsigned long long* mmbits,
                       int* niter, int* conv) {
    int t = blockIdx.x * blockDim.x + threadIdx.x;
    if (t < NN) { colcnt[t] = 0; colfill[t] = 0; }
    if (t < BB) { niter[t] = -1; conv[t] = 0; }
    if (t < 4) mmbits[t] = 0ull;
}

// transpose f32: in (R,C) row-major -> out (C,R); optional duplicate out2
__global__ void k_transpose_f32(const float* __restrict__ in, float* __restrict__ out,
                                float* __restrict__ out2, int R, int C) {
    __shared__ float tile[64][65];
    int c0 = blockIdx.x * 64;
    int r0 = blockIdx.y * 64;
    #pragma unroll
    for (int k = 0; k < 16; k++) {
        int idx = k * 256 + threadIdx.x;
        int i = idx >> 6, j = idx & 63;
        tile[i][j] = in[(size_t)(r0 + i) * C + (c0 + j)];
    }
    __syncthreads();
    #pragma unroll
    for (int k = 0; k < 16; k++) {
        int idx = k * 256 + threadIdx.x;
        int i = idx >> 6, j = idx & 63;
        float v = tile[j][i];
        size_t o = (size_t)(c0 + i) * R + (r0 + j);
        out[o] = v;
        if (out2) out2[o] = v;
    }
}

// synd (B,M) f32 -> syndb (M,B) byte
__global__ void k_synd_t(const float* __restrict__ synd, unsigned char* __restrict__ syndb) {
    __shared__ float tile[64][65];
    int c0 = blockIdx.x * 64;   // m
    int r0 = blockIdx.y * 64;   // b
    #pragma unroll
    for (int k = 0; k < 16; k++) {
        int idx = k * 256 + threadIdx.x;
        int i = idx >> 6, j = idx & 63;
        tile[i][j] = synd[(size_t)(r0 + i) * MM + (c0 + j)];
    }
    __syncthreads();
    #pragma unroll
    for (int k = 0; k < 16; k++) {
        int idx = k * 256 + threadIdx.x;
        int i = idx >> 6, j = idx & 63;
        syndb[(size_t)(c0 + i) * BB + (r0 + j)] = (tile[j][i] != 0.0f) ? 1 : 0;
    }
}

__global__ void k_hist(const int* __restrict__ vc, int* colcnt) {
    int e = blockIdx.x * 256 + threadIdx.x;
    if (e >= MM * DEG) return;
    int c = vc[e];
    if (c < NN) atomicAdd(&colcnt[c], 1);
}

__global__ void k_scan(const int* __restrict__ colcnt, int* __restrict__ colptr) {
    __shared__ int part[256];
    __shared__ int base[257];
    int t = threadIdx.x;
    int s = 0;
    for (int i = 0; i < 64; i++) s += colcnt[t * 64 + i];
    part[t] = s;
    __syncthreads();
    if (t == 0) {
        int acc = 0;
        for (int i = 0; i < 256; i++) { base[i] = acc; acc += part[i]; }
        base[256] = acc;
    }
    __syncthreads();
    int acc = base[t];
    for (int i = 0; i < 64; i++) { int c = t * 64 + i; colptr[c] = acc; acc += colcnt[c]; }
    if (t == 255) colptr[NN] = base[256];
}

__global__ void k_fill(const int* __restrict__ vc, const int* __restrict__ colptr,
                       int* colfill, int* coledges) {
    int e = blockIdx.x * 256 + threadIdx.x;
    if (e >= MM * DEG) return;
    int c = vc[e];
    if (c < NN) {
        int p = colptr[c] + atomicAdd(&colfill[c], 1);
        coledges[p] = e;
    }
}

// deterministic: sort each column's edge list ascending (order-independent result)
__global__ void k_sort(const int* __restrict__ colptr, int* coledges) {
    int n = blockIdx.x * 256 + threadIdx.x;
    if (n >= NN) return;
    int p0 = colptr[n], p1 = colptr[n + 1];
    for (int i = p0 + 1; i < p1; i++) {
        int v = coledges[i];
        int j = i - 1;
        while (j >= p0 && coledges[j] > v) { coledges[j + 1] = coledges[j]; j--; }
        coledges[j + 1] = v;
    }
}

// ---------------- iteration kernels ----------------

// check-node update, with fused parity check of the PREVIOUS iteration's e_v.
// block = m, thread = b
__global__ void k_check(const int* __restrict__ vc, const float* __restrict__ lv,
                        float* __restrict__ msg, const unsigned char* __restrict__ syndb,
                        const int* __restrict__ niter, unsigned long long* __restrict__ mmbits,
                        float beta, int first) {
    __shared__ int cs[DEG];
    int m = blockIdx.x, b = threadIdx.x;
    if (threadIdx.x < DEG) cs[threadIdx.x] = vc[m * DEG + threadIdx.x];
    __syncthreads();
    if (niter[b] != -1) return;

    float ab[DEG];
    float m0 = INFINITY, m1 = INFINITY;
    unsigned neg = 0, epar = 0;
    #pragma unroll
    for (int d = 0; d < DEG; d++) {
        int c = cs[d];
        float a;
        if (c >= NN) {
            a = INFINITY;
        } else {
            float g = lv[(size_t)c * BB + b];
            epar ^= (g <= 0.0f) ? 1u : 0u;                 // e_v bit of prev iteration
            if (first) a = g;
            else       a = g - msg[(size_t)(m * DEG + d) * BB + b];
        }
        if (!(a > 0.0f)) neg |= 1u << d;   // sign(a<=0) = -1 (matches sign(0)->-1)
        float x = fabsf(a);
        ab[d] = x;
        if (x < m0) { m1 = m0; m0 = x; }
        else if (x < m1) { m1 = x; }
    }
    unsigned sb = syndb[(size_t)m * BB + b] ? 1u : 0u;

    // fused parity for iteration i-1 (not defined for the first iteration)
    if (!first) {
        bool mism = (epar != sb);
        unsigned long long bal = __ballot(mism);
        if (bal) {
            int w = b >> 6;
            unsigned long long seen = mmbits[w];
            unsigned long long fresh = bal & ~seen;
            if (fresh && ((unsigned)(b & 63) == (unsigned)(__ffsll((long long)bal) - 1)))
                atomicOr(&mmbits[w], bal);
        }
    }

    unsigned q = (__popc(neg) & 1u) ^ sb;
    #pragma unroll
    for (int d = 0; d < DEG; d++) {
        int c = cs[d];
        if (c >= NN) continue;            // dummy: b masked to 0, never read
        float mr = (ab[d] == m0) ? m1 : m0;   // value-equality: exact tie semantics
        float t = beta * mr;                  // single rounding, sign applied exactly
        unsigned s = q ^ ((neg >> d) & 1u);
        msg[(size_t)(m * DEG + d) * BB + b] = s ? -t : t;
    }
}

// variable-node update: block = n, thread = b; deterministic ascending-edge sum
__global__ void k_var(const float* __restrict__ llr0t, const float* __restrict__ msg,
                      const int* __restrict__ colptr, const int* __restrict__ coledges,
                      float* __restrict__ lv, const int* __restrict__ niter) {
    int n = blockIdx.x, b = threadIdx.x;
    if (niter[b] != -1) return;           // frozen batches keep their converged lv
    float s = llr0t[(size_t)n * BB + b];
    int p0 = colptr[n], p1 = colptr[n + 1];
    for (int p = p0; p < p1; p++) {
        int e = coledges[p];
        s += msg[(size_t)e * BB + b];
    }
    lv[(size_t)n * BB + b] = s;
}

// standalone parity for the final iteration (conv flag at i = MAX_ITER)
__global__ void k_parity_f(const int* __restrict__ vc, const float* __restrict__ lv,
                           const unsigned char* __restrict__ syndb,
                           const int* __restrict__ niter, unsigned long long* __restrict__ mmbits) {
    __shared__ int cs[DEG];
    int m = blockIdx.x, b = threadIdx.x;
    if (threadIdx.x < DEG) cs[threadIdx.x] = vc[m * DEG + threadIdx.x];
    __syncthreads();
    if (niter[b] != -1) return;
    unsigned epar = 0;
    #pragma unroll
    for (int d = 0; d < DEG; d++) {
        int c = cs[d];
        if (c < NN) {
            float g = lv[(size_t)c * BB + b];
            epar ^= (g <= 0.0f) ? 1u : 0u;
        }
    }
    unsigned sb = syndb[(size_t)m * BB + b] ? 1u : 0u;
    bool mism = (epar != sb);
    unsigned long long bal = __ballot(mism);
    if (bal) {
        int w = b >> 6;
        unsigned long long seen = mmbits[w];
        unsigned long long fresh = bal & ~seen;
        if (fresh && ((unsigned)(b & 63) == (unsigned)(__ffsll((long long)bal) - 1)))
            atomicOr(&mmbits[w], bal);
    }
}

// finalize convergence for iteration `it`, then reset mmbits
__global__ void k_conv(int* niter, int* conv, unsigned long long* mmbits, int it) {
    int b = threadIdx.x;
    unsigned long long w = mmbits[b >> 6];
    bool pass = !((w >> (b & 63)) & 1ull);
    __syncthreads();
    if (niter[b] == -1 && pass) { niter[b] = it; conv[b] = 1; }
    if (b < 4) mmbits[b] = 0ull;
}

// ---------------- epilogue ----------------

__global__ void k_out_e(const float* __restrict__ lv, float* __restrict__ out) {
    __shared__ float tile[64][65];
    int c0 = blockIdx.x * 64;   // b
    int r0 = blockIdx.y * 64;   // n
    #pragma unroll
    for (int k = 0; k < 16; k++) {
        int idx = k * 256 + threadIdx.x;
        int i = idx >> 6, j = idx & 63;
        tile[i][j] = (lv[(size_t)(r0 + i) * BB + (c0 + j)] <= 0.0f) ? 1.0f : 0.0f;
    }
    __syncthreads();
    #pragma unroll
    for (int k = 0; k < 16; k++) {
        int idx = k * 256 + threadIdx.x;
        int i = idx >> 6, j = idx & 63;
        out[(size_t)(c0 + i) * NN + (r0 + j)] = tile[j][i];
    }
}

__global__ void k_out_scalars(const int* __restrict__ niter, const int* __restrict__ conv,
                              float* __restrict__ out_ni, float* __restrict__ out_conv) {
    int b = threadIdx.x;
    int ni = niter[b];
    out_ni[b] = (float)(ni == -1 ? MAX_ITER : ni);
    out_conv[b] = (float)conv[b];
}

// ---------------- launch ----------------

extern "C" void kernel_launch(void* const* d_in, const int* in_sizes, int n_in,
                              void* d_out, int out_size, void* d_ws, size_t ws_size,
                              hipStream_t stream) {
    const float* synd = (const float*)d_in[0];   // (B, M)
    const float* llr0 = (const float*)d_in[1];   // (B, N)
    const int* vcol   = (const int*)d_in[3];     // (M, DEG)
    float* out = (float*)d_out;

    char* ws = (char*)d_ws;
    size_t off = 0;
    auto alloc = [&](size_t bytes) {
        off = (off + 255) & ~(size_t)255;
        size_t o = off; off += bytes; return o;
    };
    float* llr0t   = (float*)(ws + alloc((size_t)NN * BB * 4));
    float* lv      = (float*)(ws + alloc((size_t)NN * BB * 4));
    float* msg     = (float*)(ws + alloc((size_t)MM * DEG * BB * 4));
    unsigned char* syndb = (unsigned char*)(ws + alloc((size_t)MM * BB));
    int* coledges = (int*)(ws + alloc((size_t)MM * DEG * 4));
    int* colptr   = (int*)(ws + alloc((size_t)(NN + 1) * 4));
    int* colcnt   = (int*)(ws + alloc((size_t)NN * 4));
    int* colfill  = (int*)(ws + alloc((size_t)NN * 4));
    unsigned long long* mmbits = (unsigned long long*)(ws + alloc(4 * 8));
    int* niter    = (int*)(ws + alloc((size_t)BB * 4));
    int* conv     = (int*)(ws + alloc((size_t)BB * 4));
    (void)ws_size; (void)in_sizes; (void)n_in; (void)out_size;

    // prologue
    k_init<<<NN / 256, 256, 0, stream>>>(colcnt, colfill, mmbits, niter, conv);
    k_transpose_f32<<<dim3(NN / 64, BB / 64), 256, 0, stream>>>(llr0, llr0t, lv, BB, NN);
    k_synd_t<<<dim3(MM / 64, BB / 64), 256, 0, stream>>>(synd, syndb);
    k_hist<<<(MM * DEG + 255) / 256, 256, 0, stream>>>(vcol, colcnt);
    k_scan<<<1, 256, 0, stream>>>(colcnt, colptr);
    k_fill<<<(MM * DEG + 255) / 256, 256, 0, stream>>>(vcol, colptr, colfill, coledges);
    k_sort<<<NN / 256, 256, 0, stream>>>(colptr, coledges);

    // main loop: k_check(i) fuses the parity/convergence test of iteration i-1
    for (int i = 1; i <= MAX_ITER; i++) {
        float beta = 1.0f - ldexpf(1.0f, -i);
        k_check<<<MM, 256, 0, stream>>>(vcol, lv, msg, syndb, niter, mmbits, beta, (i == 1) ? 1 : 0);
        if (i >= 2)
            k_conv<<<1, 256, 0, stream>>>(niter, conv, mmbits, i - 1);
        k_var<<<NN, 256, 0, stream>>>(llr0t, msg, colptr, coledges, lv, niter);
    }
    // final parity (conv flag for iteration MAX_ITER)
    k_parity_f<<<MM, 256, 0, stream>>>(vcol, lv, syndb, niter, mmbits);
    k_conv<<<1, 256, 0, stream>>>(niter, conv, mmbits, MAX_ITER);

    // epilogue: e_out | num_iters | l_out | conv
    size_t off_e = 0;
    size_t off_ni = (size_t)BB * NN;
    size_t off_l = off_ni + BB;
    size_t off_c = off_l + (size_t)BB * NN;
    k_out_e<<<dim3(BB / 64, NN / 64), 256, 0, stream>>>(lv, out + off_e);
    k_transpose_f32<<<dim3(BB / 64, NN / 64), 256, 0, stream>>>(lv, out + off_l, nullptr, NN, BB);
    k_out_scalars<<<1, 256, 0, stream>>>(niter, conv, out + off_ni, out + off_c);
}

// Round 3
// 2268.282 us; speedup vs baseline: 1.9010x; 1.9010x over previous
//
#include <hip/hip_runtime.h>
#include <cmath>
#include <cstdint>
#include <cstddef>

#define BB 256      // batch
#define MM 8192     // checks
#define NN 16384    // variables
#define DEG 10
#define MAX_ITER 30
#define PAR_BLOCKS 64

// ---------------- prologue kernels ----------------

__global__ void k_init(int* colcnt, int* colfill, int* mm, int* niter, int* conv) {
    int t = blockIdx.x * blockDim.x + threadIdx.x;
    if (t < NN) { colcnt[t] = 0; colfill[t] = 0; }
    if (t < BB) { mm[t] = 0; niter[t] = -1; conv[t] = 0; }
}

// transpose f32: in (R,C) row-major -> out (C,R); optional duplicate out2
__global__ void k_transpose_f32(const float* __restrict__ in, float* __restrict__ out,
                                float* __restrict__ out2, int R, int C) {
    __shared__ float tile[64][65];
    int c0 = blockIdx.x * 64;
    int r0 = blockIdx.y * 64;
    #pragma unroll
    for (int k = 0; k < 16; k++) {
        int idx = k * 256 + threadIdx.x;
        int i = idx >> 6, j = idx & 63;
        tile[i][j] = in[(size_t)(r0 + i) * C + (c0 + j)];
    }
    __syncthreads();
    #pragma unroll
    for (int k = 0; k < 16; k++) {
        int idx = k * 256 + threadIdx.x;
        int i = idx >> 6, j = idx & 63;
        float v = tile[j][i];
        size_t o = (size_t)(c0 + i) * R + (r0 + j);
        out[o] = v;
        if (out2) out2[o] = v;
    }
}

// synd (B,M) f32 -> syndb (M,B) byte
__global__ void k_synd_t(const float* __restrict__ synd, unsigned char* __restrict__ syndb) {
    __shared__ float tile[64][65];
    int c0 = blockIdx.x * 64;   // m
    int r0 = blockIdx.y * 64;   // b
    #pragma unroll
    for (int k = 0; k < 16; k++) {
        int idx = k * 256 + threadIdx.x;
        int i = idx >> 6, j = idx & 63;
        tile[i][j] = synd[(size_t)(r0 + i) * MM + (c0 + j)];
    }
    __syncthreads();
    #pragma unroll
    for (int k = 0; k < 16; k++) {
        int idx = k * 256 + threadIdx.x;
        int i = idx >> 6, j = idx & 63;
        syndb[(size_t)(c0 + i) * BB + (r0 + j)] = (tile[j][i] != 0.0f) ? 1 : 0;
    }
}

__global__ void k_hist(const int* __restrict__ vc, int* colcnt) {
    int e = blockIdx.x * 256 + threadIdx.x;
    if (e >= MM * DEG) return;
    int c = vc[e];
    if (c < NN) atomicAdd(&colcnt[c], 1);
}

__global__ void k_scan(const int* __restrict__ colcnt, int* __restrict__ colptr) {
    __shared__ int part[256];
    __shared__ int base[257];
    int t = threadIdx.x;
    int s = 0;
    for (int i = 0; i < 64; i++) s += colcnt[t * 64 + i];
    part[t] = s;
    __syncthreads();
    if (t == 0) {
        int acc = 0;
        for (int i = 0; i < 256; i++) { base[i] = acc; acc += part[i]; }
        base[256] = acc;
    }
    __syncthreads();
    int acc = base[t];
    for (int i = 0; i < 64; i++) { int c = t * 64 + i; colptr[c] = acc; acc += colcnt[c]; }
    if (t == 255) colptr[NN] = base[256];
}

__global__ void k_fill(const int* __restrict__ vc, const int* __restrict__ colptr,
                       int* colfill, int* coledges) {
    int e = blockIdx.x * 256 + threadIdx.x;
    if (e >= MM * DEG) return;
    int c = vc[e];
    if (c < NN) {
        int p = colptr[c] + atomicAdd(&colfill[c], 1);
        coledges[p] = e;
    }
}

// deterministic: sort each column's edge list ascending (order-independent result)
__global__ void k_sort(const int* __restrict__ colptr, int* coledges) {
    int n = blockIdx.x * 256 + threadIdx.x;
    if (n >= NN) return;
    int p0 = colptr[n], p1 = colptr[n + 1];
    for (int i = p0 + 1; i < p1; i++) {
        int v = coledges[i];
        int j = i - 1;
        while (j >= p0 && coledges[j] > v) { coledges[j + 1] = coledges[j]; j--; }
        coledges[j + 1] = v;
    }
}

// ---------------- iteration kernels ----------------

// check-node update: block = m, thread = b
__global__ void k_check(const int* __restrict__ vc, const float* __restrict__ lv,
                        float* __restrict__ msg, const unsigned char* __restrict__ syndb,
                        const int* __restrict__ niter, float beta, int first) {
    __shared__ int cs[DEG];
    int m = blockIdx.x, b = threadIdx.x;
    if (threadIdx.x < DEG) cs[threadIdx.x] = vc[m * DEG + threadIdx.x];
    __syncthreads();
    if (niter[b] != -1) return;

    float ab[DEG];
    float m0 = INFINITY, m1 = INFINITY;
    unsigned neg = 0;
    #pragma unroll
    for (int d = 0; d < DEG; d++) {
        int c = cs[d];
        float a;
        if (c >= NN) {
            a = INFINITY;
        } else {
            float g = lv[(size_t)c * BB + b];
            if (first) a = g;
            else       a = g - msg[(size_t)(m * DEG + d) * BB + b];
        }
        if (!(a > 0.0f)) neg |= 1u << d;   // sign(a<=0) = -1 (matches sign(0)->-1)
        float x = fabsf(a);
        ab[d] = x;
        if (x < m0) { m1 = m0; m0 = x; }
        else if (x < m1) { m1 = x; }
    }
    unsigned q = (__popc(neg) & 1u) ^ (syndb[(size_t)m * BB + b] ? 1u : 0u);
    #pragma unroll
    for (int d = 0; d < DEG; d++) {
        int c = cs[d];
        if (c >= NN) continue;            // dummy: b masked to 0, never read
        float mr = (ab[d] == m0) ? m1 : m0;   // value-equality: exact tie semantics
        float t = beta * mr;                  // single rounding, sign applied exactly
        unsigned s = q ^ ((neg >> d) & 1u);
        msg[(size_t)(m * DEG + d) * BB + b] = s ? -t : t;
    }
}

// variable-node update: block = n, thread = b; deterministic ascending-edge sum
__global__ void k_var(const float* __restrict__ llr0t, const float* __restrict__ msg,
                      const int* __restrict__ colptr, const int* __restrict__ coledges,
                      float* __restrict__ lv, unsigned char* __restrict__ ev,
                      const int* __restrict__ niter) {
    int n = blockIdx.x, b = threadIdx.x;
    if (niter[b] != -1) return;           // frozen batches keep their converged lv/ev
    float s = llr0t[(size_t)n * BB + b];
    int p0 = colptr[n], p1 = colptr[n + 1];
    for (int p = p0; p < p1; p++) {
        int e = coledges[p];
        s += msg[(size_t)e * BB + b];
    }
    lv[(size_t)n * BB + b] = s;
    ev[(size_t)n * BB + b] = (s <= 0.0f) ? 1 : 0;
}

// persistent grid-strided parity with block-level early exit.
// mm[b] is set-only within an iteration -> final state is deterministic; the
// early exit only skips work that cannot change mm.
__global__ void k_parity(const int* __restrict__ vc, const unsigned char* __restrict__ ev,
                         const unsigned char* __restrict__ syndb, const int* __restrict__ niter,
                         int* __restrict__ mm) {
    __shared__ int s_all;
    int b = threadIdx.x;
    bool frozen = (niter[b] != -1);
    volatile int* vmm = (volatile int*)mm;

    for (int m = blockIdx.x; m < MM; m += PAR_BLOCKS) {
        // vote: are all batches already flagged (mismatch found or frozen)?
        if (threadIdx.x == 0) s_all = 1;
        __syncthreads();
        bool flagged = frozen || (vmm[b] != 0);
        if (!flagged) s_all = 0;
        __syncthreads();
        if (s_all) return;
        if (flagged) continue;            // lane masked off; others proceed

        unsigned par = 0;
        #pragma unroll
        for (int d = 0; d < DEG; d++) {
            int c = vc[m * DEG + d];
            if (c < NN) par ^= ev[(size_t)c * BB + b];
        }
        if ((par & 1u) != (unsigned)syndb[(size_t)m * BB + b]) atomicOr(&mm[b], 1);
    }
}

__global__ void k_conv(int* niter, int* conv, int* mm, int it) {
    int b = threadIdx.x;
    if (niter[b] == -1 && mm[b] == 0) { niter[b] = it; conv[b] = 1; }
    mm[b] = 0;                            // reset for next iteration
}

// ---------------- epilogue ----------------

__global__ void k_out_e(const unsigned char* __restrict__ ev, float* __restrict__ out) {
    __shared__ float tile[64][65];
    int c0 = blockIdx.x * 64;   // b
    int r0 = blockIdx.y * 64;   // n
    #pragma unroll
    for (int k = 0; k < 16; k++) {
        int idx = k * 256 + threadIdx.x;
        int i = idx >> 6, j = idx & 63;
        tile[i][j] = (float)ev[(size_t)(r0 + i) * BB + (c0 + j)];
    }
    __syncthreads();
    #pragma unroll
    for (int k = 0; k < 16; k++) {
        int idx = k * 256 + threadIdx.x;
        int i = idx >> 6, j = idx & 63;
        out[(size_t)(c0 + i) * NN + (r0 + j)] = tile[j][i];
    }
}

__global__ void k_out_scalars(const int* __restrict__ niter, const int* __restrict__ conv,
                              float* __restrict__ out_ni, float* __restrict__ out_conv) {
    int b = threadIdx.x;
    int ni = niter[b];
    out_ni[b] = (float)(ni == -1 ? MAX_ITER : ni);
    out_conv[b] = (float)conv[b];
}

// ---------------- launch ----------------

extern "C" void kernel_launch(void* const* d_in, const int* in_sizes, int n_in,
                              void* d_out, int out_size, void* d_ws, size_t ws_size,
                              hipStream_t stream) {
    const float* synd = (const float*)d_in[0];   // (B, M)
    const float* llr0 = (const float*)d_in[1];   // (B, N)
    const int* vcol   = (const int*)d_in[3];     // (M, DEG)
    float* out = (float*)d_out;

    char* ws = (char*)d_ws;
    size_t off = 0;
    auto alloc = [&](size_t bytes) {
        off = (off + 255) & ~(size_t)255;
        size_t o = off; off += bytes; return o;
    };
    float* llr0t   = (float*)(ws + alloc((size_t)NN * BB * 4));
    float* lv      = (float*)(ws + alloc((size_t)NN * BB * 4));
    float* msg     = (float*)(ws + alloc((size_t)MM * DEG * BB * 4));
    unsigned char* ev    = (unsigned char*)(ws + alloc((size_t)NN * BB));
    unsigned char* syndb = (unsigned char*)(ws + alloc((size_t)MM * BB));
    int* coledges = (int*)(ws + alloc((size_t)MM * DEG * 4));
    int* colptr   = (int*)(ws + alloc((size_t)(NN + 1) * 4));
    int* colcnt   = (int*)(ws + alloc((size_t)NN * 4));
    int* colfill  = (int*)(ws + alloc((size_t)NN * 4));
    int* mm       = (int*)(ws + alloc((size_t)BB * 4));
    int* niter    = (int*)(ws + alloc((size_t)BB * 4));
    int* conv     = (int*)(ws + alloc((size_t)BB * 4));
    (void)ws_size; (void)in_sizes; (void)n_in; (void)out_size;

    // prologue
    k_init<<<NN / 256, 256, 0, stream>>>(colcnt, colfill, mm, niter, conv);
    k_transpose_f32<<<dim3(NN / 64, BB / 64), 256, 0, stream>>>(llr0, llr0t, lv, BB, NN);
    k_synd_t<<<dim3(MM / 64, BB / 64), 256, 0, stream>>>(synd, syndb);
    k_hist<<<(MM * DEG + 255) / 256, 256, 0, stream>>>(vcol, colcnt);
    k_scan<<<1, 256, 0, stream>>>(colcnt, colptr);
    k_fill<<<(MM * DEG + 255) / 256, 256, 0, stream>>>(vcol, colptr, colfill, coledges);
    k_sort<<<NN / 256, 256, 0, stream>>>(colptr, coledges);

    // main loop
    for (int i = 1; i <= MAX_ITER; i++) {
        float beta = 1.0f - ldexpf(1.0f, -i);
        k_check<<<MM, 256, 0, stream>>>(vcol, lv, msg, syndb, niter, beta, (i == 1) ? 1 : 0);
        k_var<<<NN, 256, 0, stream>>>(llr0t, msg, colptr, coledges, lv, ev, niter);
        k_parity<<<PAR_BLOCKS, 256, 0, stream>>>(vcol, ev, syndb, niter, mm);
        k_conv<<<1, 256, 0, stream>>>(niter, conv, mm, i);
    }

    // epilogue: e_out | num_iters | l_out | conv
    size_t off_e = 0;
    size_t off_ni = (size_t)BB * NN;
    size_t off_l = off_ni + BB;
    size_t off_c = off_l + (size_t)BB * NN;
    k_out_e<<<dim3(BB / 64, NN / 64), 256, 0, stream>>>(ev, out + off_e);
    k_transpose_f32<<<dim3(BB / 64, NN / 64), 256, 0, stream>>>(lv, out + off_l, nullptr, NN, BB);
    k_out_scalars<<<1, 256, 0, stream>>>(niter, conv, out + off_ni, out + off_c);
}

// Round 4
// 2007.096 us; speedup vs baseline: 2.1484x; 1.1301x over previous
//
#include <hip/hip_runtime.h>
#include <cmath>
#include <cstdint>
#include <cstddef>

#define BB 256      // batch
#define MM 8192     // checks
#define NN 16384    // variables
#define DEG 10
#define MAX_ITER 30
#define PAR_BLOCKS 64

typedef unsigned char  u8;
typedef unsigned short u16;

// ---------------- prologue kernels ----------------

__global__ void k_init(int* colcnt, int* colfill, int* mm, int* niter, int* conv, int* cnt) {
    int t = blockIdx.x * blockDim.x + threadIdx.x;
    if (t < NN) { colcnt[t] = 0; colfill[t] = 0; }
    if (t < BB) { mm[t] = 0; niter[t] = -1; conv[t] = 0; }
    if (t == 0) *cnt = 0;
}

// transpose f32: in (R,C) row-major -> out (C,R); optional duplicate out2
__global__ void k_transpose_f32(const float* __restrict__ in, float* __restrict__ out,
                                float* __restrict__ out2, int R, int C) {
    __shared__ float tile[64][65];
    int c0 = blockIdx.x * 64;
    int r0 = blockIdx.y * 64;
    #pragma unroll
    for (int k = 0; k < 16; k++) {
        int idx = k * 256 + threadIdx.x;
        int i = idx >> 6, j = idx & 63;
        tile[i][j] = in[(size_t)(r0 + i) * C + (c0 + j)];
    }
    __syncthreads();
    #pragma unroll
    for (int k = 0; k < 16; k++) {
        int idx = k * 256 + threadIdx.x;
        int i = idx >> 6, j = idx & 63;
        float v = tile[j][i];
        size_t o = (size_t)(c0 + i) * R + (r0 + j);
        out[o] = v;
        if (out2) out2[o] = v;
    }
}

// synd (B,M) f32 -> syndb (M,B) byte
__global__ void k_synd_t(const float* __restrict__ synd, u8* __restrict__ syndb) {
    __shared__ float tile[64][65];
    int c0 = blockIdx.x * 64;   // m
    int r0 = blockIdx.y * 64;   // b
    #pragma unroll
    for (int k = 0; k < 16; k++) {
        int idx = k * 256 + threadIdx.x;
        int i = idx >> 6, j = idx & 63;
        tile[i][j] = synd[(size_t)(r0 + i) * MM + (c0 + j)];
    }
    __syncthreads();
    #pragma unroll
    for (int k = 0; k < 16; k++) {
        int idx = k * 256 + threadIdx.x;
        int i = idx >> 6, j = idx & 63;
        syndb[(size_t)(c0 + i) * BB + (r0 + j)] = (tile[j][i] != 0.0f) ? 1 : 0;
    }
}

__global__ void k_hist(const int* __restrict__ vc, int* colcnt) {
    int e = blockIdx.x * 256 + threadIdx.x;
    if (e >= MM * DEG) return;
    int c = vc[e];
    if (c < NN) atomicAdd(&colcnt[c], 1);
}

__global__ void k_scan(const int* __restrict__ colcnt, int* __restrict__ colptr) {
    __shared__ int part[256];
    __shared__ int base[257];
    int t = threadIdx.x;
    int s = 0;
    for (int i = 0; i < 64; i++) s += colcnt[t * 64 + i];
    part[t] = s;
    __syncthreads();
    if (t == 0) {
        int acc = 0;
        for (int i = 0; i < 256; i++) { base[i] = acc; acc += part[i]; }
        base[256] = acc;
    }
    __syncthreads();
    int acc = base[t];
    for (int i = 0; i < 64; i++) { int c = t * 64 + i; colptr[c] = acc; acc += colcnt[c]; }
    if (t == 255) colptr[NN] = base[256];
}

__global__ void k_fill(const int* __restrict__ vc, const int* __restrict__ colptr,
                       int* colfill, int* coledges) {
    int e = blockIdx.x * 256 + threadIdx.x;
    if (e >= MM * DEG) return;
    int c = vc[e];
    if (c < NN) {
        int p = colptr[c] + atomicAdd(&colfill[c], 1);
        coledges[p] = e;
    }
}

// deterministic: sort each column's edge list ascending (order-independent result)
__global__ void k_sort(const int* __restrict__ colptr, int* coledges) {
    int n = blockIdx.x * 256 + threadIdx.x;
    if (n >= NN) return;
    int p0 = colptr[n], p1 = colptr[n + 1];
    for (int i = p0 + 1; i < p1; i++) {
        int v = coledges[i];
        int j = i - 1;
        while (j >= p0 && coledges[j] > v) { coledges[j + 1] = coledges[j]; j--; }
        coledges[j + 1] = v;
    }
}

// ---------------- iteration kernels ----------------

// check-node update. block = m, thread handles batches (2t, 2t+1).
// msg_prev is reconstructed from compact state {v0=beta*min0, v1=beta*min1,
// neg bits, q, argmin-index} written by the previous iteration (bit-exact:
// same multiplies; (d==i0) == (ab[d]==min0) because duplicate mins force
// min1==min0). Fallback (has_state==0): read msg_prev directly.
__global__ void k_check(const int* __restrict__ vc, const float* __restrict__ lv,
                        float* __restrict__ msg,
                        float* __restrict__ sv0, float* __restrict__ sv1,
                        u16* __restrict__ sbits, const u8* __restrict__ syndb,
                        float beta, int first, int has_state) {
    __shared__ int cs[DEG];
    int m = blockIdx.x, t = threadIdx.x;
    if (t < DEG) cs[t] = vc[m * DEG + t];
    __syncthreads();
    int b2 = t * 2;
    size_t mb = (size_t)m * BB + b2;

    float pv0x = 0.f, pv0y = 0.f, pv1x = 0.f, pv1y = 0.f;
    unsigned pbx = 0, pby = 0;
    if (!first && has_state) {
        float2 a0 = *(const float2*)(sv0 + mb);
        float2 a1 = *(const float2*)(sv1 + mb);
        ushort2 pb = *(const ushort2*)(sbits + mb);
        pv0x = a0.x; pv0y = a0.y; pv1x = a1.x; pv1y = a1.y;
        pbx = pb.x; pby = pb.y;
    }
    int pi0x = (pbx >> 11) & 15, pi0y = (pby >> 11) & 15;
    unsigned pqx = (pbx >> 10) & 1u, pqy = (pby >> 10) & 1u;

    float m0x = INFINITY, m1x = INFINITY, m0y = INFINITY, m1y = INFINITY;
    unsigned negx = 0, negy = 0;
    int i0x = 0, i0y = 0;

    #pragma unroll
    for (int d = 0; d < DEG; d++) {
        int c = cs[d];
        float ax, ay;
        if (c >= NN) {
            ax = INFINITY; ay = INFINITY;
        } else {
            float2 g = *(const float2*)(lv + (size_t)c * BB + b2);
            if (first) { ax = g.x; ay = g.y; }
            else if (has_state) {
                float tx = (d == pi0x) ? pv1x : pv0x;
                float ty = (d == pi0y) ? pv1y : pv0y;
                unsigned sx = pqx ^ ((pbx >> d) & 1u);
                unsigned sy = pqy ^ ((pby >> d) & 1u);
                ax = g.x - (sx ? -tx : tx);
                ay = g.y - (sy ? -ty : ty);
            } else {
                float2 mp = *(const float2*)(msg + (size_t)(m * DEG + d) * BB + b2);
                ax = g.x - mp.x; ay = g.y - mp.y;
            }
        }
        if (!(ax > 0.0f)) negx |= 1u << d;   // sign(a<=0) = -1 (matches ref sign(0)->-1)
        if (!(ay > 0.0f)) negy |= 1u << d;
        float xx = fabsf(ax), xy = fabsf(ay);
        if (xx < m0x) { m1x = m0x; m0x = xx; i0x = d; } else if (xx < m1x) m1x = xx;
        if (xy < m0y) { m1y = m0y; m0y = xy; i0y = d; } else if (xy < m1y) m1y = xy;
    }
    uchar2 sb = *(const uchar2*)(syndb + mb);
    unsigned qx = (__popc(negx) & 1u) ^ (sb.x ? 1u : 0u);
    unsigned qy = (__popc(negy) & 1u) ^ (sb.y ? 1u : 0u);
    float v0x = beta * m0x, v1x = beta * m1x;   // exact: same single multiplies as ref
    float v0y = beta * m0y, v1y = beta * m1y;

    if (has_state) {
        *(float2*)(sv0 + mb) = make_float2(v0x, v0y);
        *(float2*)(sv1 + mb) = make_float2(v1x, v1y);
        ushort2 nb;
        nb.x = (u16)(negx | (qx << 10) | ((unsigned)i0x << 11));
        nb.y = (u16)(negy | (qy << 10) | ((unsigned)i0y << 11));
        *(ushort2*)(sbits + mb) = nb;
    }
    #pragma unroll
    for (int d = 0; d < DEG; d++) {
        int c = cs[d];
        if (c >= NN) continue;            // dummy: masked to 0 in ref, never summed
        float tx = (d == i0x) ? v1x : v0x;
        float ty = (d == i0y) ? v1y : v0y;
        unsigned sx = qx ^ ((negx >> d) & 1u);
        unsigned sy = qy ^ ((negy >> d) & 1u);
        *(float2*)(msg + (size_t)(m * DEG + d) * BB + b2) =
            make_float2(sx ? -tx : tx, sy ? -ty : ty);
    }
}

// variable-node update: block = n, thread handles batches (2t, 2t+1);
// deterministic ascending-edge sum. Frozen batches keep their converged lv.
__global__ void k_var(const float* __restrict__ llr0t, const float* __restrict__ msg,
                      const int* __restrict__ colptr, const int* __restrict__ coledges,
                      float* __restrict__ lv, const int* __restrict__ niter) {
    int n = blockIdx.x, t = threadIdx.x, b2 = t * 2;
    int f0 = niter[b2], f1 = niter[b2 + 1];
    if (f0 != -1 && f1 != -1) return;
    float2 s = *(const float2*)(llr0t + (size_t)n * BB + b2);
    int p0 = colptr[n], p1 = colptr[n + 1];
    for (int p = p0; p < p1; p++) {
        int e = coledges[p];
        float2 mv = *(const float2*)(msg + (size_t)e * BB + b2);
        s.x += mv.x; s.y += mv.y;
    }
    float* dst = lv + (size_t)n * BB + b2;
    if (f0 == -1 && f1 == -1) *(float2*)dst = s;
    else if (f0 == -1) dst[0] = s.x;
    else dst[1] = s.y;
}

// persistent grid-strided parity (reads lv signs) with block-level early exit,
// convergence finalization folded into the last-finishing block (ticket).
// mm[b] is set-only within an iteration -> deterministic final state.
__global__ void k_parity(const int* __restrict__ vc, const float* __restrict__ lv,
                         const u8* __restrict__ syndb, int* __restrict__ niter,
                         int* __restrict__ conv, int* __restrict__ mm,
                         int* __restrict__ cnt, int it) {
    __shared__ int s_stop, s_last;
    int b = threadIdx.x;
    bool frozen = (niter[b] != -1);
    volatile int* vmm = (volatile int*)mm;

    for (int m = blockIdx.x; m < MM; m += PAR_BLOCKS) {
        if (b == 0) s_stop = 1;
        __syncthreads();
        bool flagged = frozen || (vmm[b] != 0);
        if (!flagged) s_stop = 0;
        __syncthreads();
        if (s_stop) break;
        if (!flagged) {
            unsigned par = 0;
            #pragma unroll
            for (int d = 0; d < DEG; d++) {
                int c = vc[m * DEG + d];
                if (c < NN) par ^= (lv[(size_t)c * BB + b] <= 0.0f) ? 1u : 0u;
            }
            if (par != (unsigned)syndb[(size_t)m * BB + b]) atomicOr(&mm[b], 1);
        }
    }
    __syncthreads();
    __threadfence();
    if (b == 0) {
        int tk = atomicAdd(cnt, 1);
        s_last = (tk == PAR_BLOCKS - 1) ? 1 : 0;
    }
    __syncthreads();
    if (s_last) {
        __threadfence();
        if (niter[b] == -1 && mm[b] == 0) { niter[b] = it; conv[b] = 1; }
        mm[b] = 0;
        if (b == 0) *cnt = 0;
    }
}

// ---------------- epilogue ----------------

__global__ void k_out_e(const float* __restrict__ lv, float* __restrict__ out) {
    __shared__ float tile[64][65];
    int c0 = blockIdx.x * 64;   // b
    int r0 = blockIdx.y * 64;   // n
    #pragma unroll
    for (int k = 0; k < 16; k++) {
        int idx = k * 256 + threadIdx.x;
        int i = idx >> 6, j = idx & 63;
        tile[i][j] = (lv[(size_t)(r0 + i) * BB + (c0 + j)] <= 0.0f) ? 1.0f : 0.0f;
    }
    __syncthreads();
    #pragma unroll
    for (int k = 0; k < 16; k++) {
        int idx = k * 256 + threadIdx.x;
        int i = idx >> 6, j = idx & 63;
        out[(size_t)(c0 + i) * NN + (r0 + j)] = tile[j][i];
    }
}

__global__ void k_out_scalars(const int* __restrict__ niter, const int* __restrict__ conv,
                              float* __restrict__ out_ni, float* __restrict__ out_conv) {
    int b = threadIdx.x;
    int ni = niter[b];
    out_ni[b] = (float)(ni == -1 ? MAX_ITER : ni);
    out_conv[b] = (float)conv[b];
}

// ---------------- launch ----------------

extern "C" void kernel_launch(void* const* d_in, const int* in_sizes, int n_in,
                              void* d_out, int out_size, void* d_ws, size_t ws_size,
                              hipStream_t stream) {
    const float* synd = (const float*)d_in[0];   // (B, M)
    const float* llr0 = (const float*)d_in[1];   // (B, N)
    const int* vcol   = (const int*)d_in[3];     // (M, DEG)
    float* out = (float*)d_out;

    char* ws = (char*)d_ws;
    size_t off = 0;
    auto alloc = [&](size_t bytes) {
        off = (off + 255) & ~(size_t)255;
        size_t o = off; off += bytes; return o;
    };
    float* llr0t   = (float*)(ws + alloc((size_t)NN * BB * 4));
    float* lv      = (float*)(ws + alloc((size_t)NN * BB * 4));
    float* msg     = (float*)(ws + alloc((size_t)MM * DEG * BB * 4));
    u8*   syndb    = (u8*)(ws + alloc((size_t)MM * BB));
    int* coledges = (int*)(ws + alloc((size_t)MM * DEG * 4));
    int* colptr   = (int*)(ws + alloc((size_t)(NN + 1) * 4));
    int* colcnt   = (int*)(ws + alloc((size_t)NN * 4));
    int* colfill  = (int*)(ws + alloc((size_t)NN * 4));
    int* mm       = (int*)(ws + alloc((size_t)BB * 4));
    int* niter    = (int*)(ws + alloc((size_t)BB * 4));
    int* conv     = (int*)(ws + alloc((size_t)BB * 4));
    int* cnt      = (int*)(ws + alloc(256));
    // optional compact check-state planes (only if workspace is big enough)
    size_t need_state = ((size_t)MM * BB) * (4 + 4 + 2) + 1024;
    int has_state = (off + need_state <= ws_size) ? 1 : 0;
    float* sv0 = nullptr; float* sv1 = nullptr; u16* sbits = nullptr;
    if (has_state) {
        sv0   = (float*)(ws + alloc((size_t)MM * BB * 4));
        sv1   = (float*)(ws + alloc((size_t)MM * BB * 4));
        sbits = (u16*)(ws + alloc((size_t)MM * BB * 2));
    }
    (void)in_sizes; (void)n_in; (void)out_size;

    // prologue
    k_init<<<NN / 256, 256, 0, stream>>>(colcnt, colfill, mm, niter, conv, cnt);
    k_transpose_f32<<<dim3(NN / 64, BB / 64), 256, 0, stream>>>(llr0, llr0t, lv, BB, NN);
    k_synd_t<<<dim3(MM / 64, BB / 64), 256, 0, stream>>>(synd, syndb);
    k_hist<<<(MM * DEG + 255) / 256, 256, 0, stream>>>(vcol, colcnt);
    k_scan<<<1, 256, 0, stream>>>(colcnt, colptr);
    k_fill<<<(MM * DEG + 255) / 256, 256, 0, stream>>>(vcol, colptr, colfill, coledges);
    k_sort<<<NN / 256, 256, 0, stream>>>(colptr, coledges);

    // main loop
    for (int i = 1; i <= MAX_ITER; i++) {
        float beta = 1.0f - ldexpf(1.0f, -i);
        k_check<<<MM, 128, 0, stream>>>(vcol, lv, msg, sv0, sv1, sbits, syndb,
                                        beta, (i == 1) ? 1 : 0, has_state);
        k_var<<<NN, 128, 0, stream>>>(llr0t, msg, colptr, coledges, lv, niter);
        k_parity<<<PAR_BLOCKS, 256, 0, stream>>>(vcol, lv, syndb, niter, conv, mm, cnt, i);
    }

    // epilogue: e_out | num_iters | l_out | conv
    size_t off_e = 0;
    size_t off_ni = (size_t)BB * NN;
    size_t off_l = off_ni + BB;
    size_t off_c = off_l + (size_t)BB * NN;
    k_out_e<<<dim3(BB / 64, NN / 64), 256, 0, stream>>>(lv, out + off_e);
    k_transpose_f32<<<dim3(BB / 64, NN / 64), 256, 0, stream>>>(lv, out + off_l, nullptr, NN, BB);
    k_out_scalars<<<1, 256, 0, stream>>>(niter, conv, out + off_ni, out + off_c);
}